// Round 16
// baseline (234.026 us; speedup 1.0000x reference)
//
#include <hip/hip_runtime.h>
#include <hip/hip_bf16.h>
#include <stdint.h>

typedef __hip_bfloat16 bf16;
typedef __attribute__((ext_vector_type(4))) float f32x4;
typedef __attribute__((ext_vector_type(8))) short s16x8;
typedef __attribute__((ext_vector_type(4))) short s16x4;

#define DEV static __device__ __forceinline__

DEV short f2bf(float f) {
  bf16 h = __float2bfloat16(f);
  short s;
  __builtin_memcpy(&s, &h, 2);
  return s;
}
DEV float bf2f(short s) {
  bf16 h;
  __builtin_memcpy(&h, &s, 2);
  return __bfloat162float(h);
}

// ------------- transpose + f32->bf16 convert: W[K][N] -> Wt[N][K] ----------
__global__ __launch_bounds__(256) void transpose_cvt(
    const float* __restrict__ W, bf16* __restrict__ Wt, int K, int N)
{
  __shared__ float tile[32][33];
  const int n0 = blockIdx.x << 5;
  const int k0 = blockIdx.y << 5;
  const int tx = threadIdx.x & 31, ty = threadIdx.x >> 5;
#pragma unroll
  for (int i = 0; i < 4; ++i)
    tile[ty + i * 8][tx] = W[(size_t)(k0 + ty + i * 8) * N + n0 + tx];
  __syncthreads();
#pragma unroll
  for (int i = 0; i < 4; ++i)
    Wt[(size_t)(n0 + ty + i * 8) * K + k0 + tx] = __float2bfloat16(tile[tx][ty + i * 8]);
}

// ------------- layernorm (f32 in, bf16 out), D = 1024 ---------------------
__global__ __launch_bounds__(256) void ln_bf16(
    const float* __restrict__ x, const float* __restrict__ g,
    const float* __restrict__ be, bf16* __restrict__ out)
{
  const int t = threadIdx.x;
  const size_t row = blockIdx.x;
  const float4 v = ((const float4*)(x + row * 1024))[t];
  float s = v.x + v.y + v.z + v.w;
  float ss = v.x * v.x + v.y * v.y + v.z * v.z + v.w * v.w;
#pragma unroll
  for (int off = 32; off > 0; off >>= 1) {
    s += __shfl_down(s, off);
    ss += __shfl_down(ss, off);
  }
  __shared__ float sh[8];
  const int wave = t >> 6, lane = t & 63;
  if (!lane) { sh[wave] = s; sh[4 + wave] = ss; }
  __syncthreads();
  s = sh[0] + sh[1] + sh[2] + sh[3];
  ss = sh[4] + sh[5] + sh[6] + sh[7];
  const float mean = s * (1.f / 1024.f);
  const float rstd = rsqrtf(ss * (1.f / 1024.f) - mean * mean + 1e-5f);
  const float4 gv = ((const float4*)g)[t];
  const float4 bv = ((const float4*)be)[t];
  s16x4 o;
  o[0] = f2bf((v.x - mean) * rstd * gv.x + bv.x);
  o[1] = f2bf((v.y - mean) * rstd * gv.y + bv.y);
  o[2] = f2bf((v.z - mean) * rstd * gv.z + bv.z);
  o[3] = f2bf((v.w - mean) * rstd * gv.w + bv.w);
  ((s16x4*)(out + row * 1024))[t] = o;
}

// ------------- residual add + layernorm ------------------------------------
__global__ __launch_bounds__(256) void add_ln_bf16(
    const float* __restrict__ a, const float* __restrict__ x,
    const float* __restrict__ g, const float* __restrict__ be,
    bf16* __restrict__ xres, bf16* __restrict__ xnorm)
{
  const int t = threadIdx.x;
  const size_t row = blockIdx.x;
  const float4 av = ((const float4*)(a + row * 1024))[t];
  const float4 xv = ((const float4*)(x + row * 1024))[t];
  float4 v;
  v.x = av.x + xv.x; v.y = av.y + xv.y; v.z = av.z + xv.z; v.w = av.w + xv.w;
  float s = v.x + v.y + v.z + v.w;
  float ss = v.x * v.x + v.y * v.y + v.z * v.z + v.w * v.w;
#pragma unroll
  for (int off = 32; off > 0; off >>= 1) {
    s += __shfl_down(s, off);
    ss += __shfl_down(ss, off);
  }
  __shared__ float sh[8];
  const int wave = t >> 6, lane = t & 63;
  if (!lane) { sh[wave] = s; sh[4 + wave] = ss; }
  __syncthreads();
  s = sh[0] + sh[1] + sh[2] + sh[3];
  ss = sh[4] + sh[5] + sh[6] + sh[7];
  const float mean = s * (1.f / 1024.f);
  const float rstd = rsqrtf(ss * (1.f / 1024.f) - mean * mean + 1e-5f);
  const float4 gv = ((const float4*)g)[t];
  const float4 bv = ((const float4*)be)[t];
  s16x4 r, o;
  r[0] = f2bf(v.x); r[1] = f2bf(v.y); r[2] = f2bf(v.z); r[3] = f2bf(v.w);
  o[0] = f2bf((v.x - mean) * rstd * gv.x + bv.x);
  o[1] = f2bf((v.y - mean) * rstd * gv.y + bv.y);
  o[2] = f2bf((v.z - mean) * rstd * gv.z + bv.z);
  o[3] = f2bf((v.w - mean) * rstd * gv.w + bv.w);
  ((s16x4*)(xres + row * 1024))[t] = r;
  ((s16x4*)(xnorm + row * 1024))[t] = o;
}

// ------------- FFN2 epilogue: out = p0 + out + bias + xnorm2 ---------------
__global__ __launch_bounds__(256) void ffn2_epi(
    const float* __restrict__ p0, float* __restrict__ out,
    const float* __restrict__ bias, const bf16* __restrict__ xn2)
{
  const int t = threadIdx.x;
  const size_t row = blockIdx.x;
  const float4 a = ((const float4*)(p0 + row * 1024))[t];
  const float4 b = ((const float4*)(out + row * 1024))[t];
  const float4 bv = ((const float4*)bias)[t];
  const s16x4 xv = ((const s16x4*)(xn2 + row * 1024))[t];
  float4 o;
  o.x = a.x + b.x + bv.x + bf2f(xv[0]);
  o.y = a.y + b.y + bv.y + bf2f(xv[1]);
  o.z = a.z + b.z + bv.z + bf2f(xv[2]);
  o.w = a.w + b.w + bv.w + bf2f(xv[3]);
  ((float4*)(out + row * 1024))[t] = o;
}

// ------------- GEMM v2: 128x128, BK=64, 2-phase dbuf, __syncthreads --------
// (R7/R10-proven structure — used for QKV, Vt)
template <int EPI>
__global__ __launch_bounds__(256) void gemm_bt(
    const bf16* __restrict__ A, const bf16* __restrict__ Bt,
    void* __restrict__ C, const float* __restrict__ bias,
    const bf16* __restrict__ add_bf16, int M, int N, int K)
{
  __shared__ bf16 sA0[128 * 64];
  __shared__ bf16 sB0[128 * 64];
  __shared__ bf16 sA1[128 * 64];
  __shared__ bf16 sB1[128 * 64];
  const int tid = threadIdx.x;
  const int wave = tid >> 6, lane = tid & 63;
  const int fr = lane & 15, fg = lane >> 4;
  const int f7 = fr & 7;
  const int wr = wave >> 1, wc = wave & 1;
  const int nbx = N >> 7;
  int bid = blockIdx.x;
  if ((gridDim.x & 7) == 0) {
    const int cpx = gridDim.x >> 3;
    bid = (bid & 7) * cpx + (bid >> 3);
  }
  const int brow = (bid / nbx) << 7;
  const int bcol = (bid % nbx) << 7;

  f32x4 acc[4][4] = {};

  const int rsub = lane >> 3;
  const int cl = (lane & 7) ^ rsub;
  size_t ga[4], gb[4];
  int la[4];
#pragma unroll
  for (int j = 0; j < 4; ++j) {
    const int r = wave * 32 + j * 8;
    ga[j] = (size_t)(brow + r + rsub) * K + cl * 8;
    gb[j] = (size_t)(bcol + r + rsub) * K + cl * 8;
    la[j] = r * 64;
  }

#define GSTAGE(SA, SB, koff)                                                   \
  do {                                                                         \
    _Pragma("unroll")                                                          \
    for (int jj = 0; jj < 4; ++jj) {                                           \
      __builtin_amdgcn_global_load_lds(                                        \
          (const __attribute__((address_space(1))) uint32_t*)(A + ga[jj] + (koff)), \
          (__attribute__((address_space(3))) uint32_t*)(&SA[la[jj]]), 16, 0, 0);  \
      __builtin_amdgcn_global_load_lds(                                        \
          (const __attribute__((address_space(1))) uint32_t*)(Bt + gb[jj] + (koff)),\
          (__attribute__((address_space(3))) uint32_t*)(&SB[la[jj]]), 16, 0, 0);  \
    }                                                                          \
  } while (0)

#define COMPUTE(SA, SB)                                                        \
  do {                                                                         \
    s16x8 af[4][2], bfr[4][2];                                                 \
    _Pragma("unroll")                                                          \
    for (int m = 0; m < 4; ++m)                                                \
      _Pragma("unroll")                                                        \
      for (int kk = 0; kk < 2; ++kk)                                           \
        af[m][kk] = *(const s16x8*)(&SA[(wr * 64 + m * 16 + fr) * 64 +         \
                                        (((kk * 4 + fg) ^ f7) << 3)]);         \
    _Pragma("unroll")                                                          \
    for (int n = 0; n < 4; ++n)                                                \
      _Pragma("unroll")                                                        \
      for (int kk = 0; kk < 2; ++kk)                                           \
        bfr[n][kk] = *(const s16x8*)(&SB[(wc * 64 + n * 16 + fr) * 64 +        \
                                         (((kk * 4 + fg) ^ f7) << 3)]);        \
    _Pragma("unroll")                                                          \
    for (int kk = 0; kk < 2; ++kk)                                             \
      _Pragma("unroll")                                                        \
      for (int m = 0; m < 4; ++m)                                              \
        _Pragma("unroll")                                                      \
        for (int n = 0; n < 4; ++n)                                            \
          acc[m][n] = __builtin_amdgcn_mfma_f32_16x16x32_bf16(                 \
              af[m][kk], bfr[n][kk], acc[m][n], 0, 0, 0);                      \
  } while (0)

  GSTAGE(sA0, sB0, 0);
  __syncthreads();

  int kt = 0;
  for (;;) {
    if (kt + 64 < K) {
      GSTAGE(sA1, sB1, kt + 64);
      COMPUTE(sA0, sB0);
      __syncthreads();
    } else {
      COMPUTE(sA0, sB0);
      break;
    }
    kt += 64;
    if (kt + 64 < K) {
      GSTAGE(sA0, sB0, kt + 64);
      COMPUTE(sA1, sB1);
      __syncthreads();
    } else {
      COMPUTE(sA1, sB1);
      break;
    }
    kt += 64;
  }
#undef GSTAGE
#undef COMPUTE

  const int crow = brow + wr * 64;
  const int ccol = bcol + wc * 64;
#pragma unroll
  for (int m = 0; m < 4; ++m) {
#pragma unroll
    for (int n = 0; n < 4; ++n) {
      const int col = ccol + n * 16 + fr;
#pragma unroll
      for (int j = 0; j < 4; ++j) {
        const int row = crow + m * 16 + fg * 4 + j;
        float v = acc[m][n][j];
        if (EPI == 0) {
          ((bf16*)C)[(size_t)row * N + col] = __float2bfloat16(v);
        } else if (EPI == 1) {
          v += bias[col];
          v = fmaxf(v, 0.f);
          ((bf16*)C)[(size_t)row * N + col] = __float2bfloat16(v);
        } else {
          float a;
          {
            bf16 hb = add_bf16[(size_t)row * N + col];
            a = __bfloat162float(hb);
          }
          ((float*)C)[(size_t)row * N + col] = v + bias[col] + a;
        }
      }
    }
  }
}

// ------------- GEMM split-K: 128x128 tile, K-half per blockIdx.y -----------
// (R14-proven; used for FFN2)
__global__ __launch_bounds__(256) void gemm_splitk(
    const bf16* __restrict__ A, const bf16* __restrict__ Bt,
    float* __restrict__ P0, float* __restrict__ P1, int M, int N, int K, int KH)
{
  __shared__ bf16 sA0[128 * 64];
  __shared__ bf16 sB0[128 * 64];
  __shared__ bf16 sA1[128 * 64];
  __shared__ bf16 sB1[128 * 64];
  const int tid = threadIdx.x;
  const int wave = tid >> 6, lane = tid & 63;
  const int fr = lane & 15, fg = lane >> 4;
  const int f7 = fr & 7;
  const int wr = wave >> 1, wc = wave & 1;
  const int nbx = N >> 7;
  int bid = blockIdx.x;
  if ((gridDim.x & 7) == 0) {
    const int cpx = gridDim.x >> 3;
    bid = (bid & 7) * cpx + (bid >> 3);
  }
  const int brow = (bid / nbx) << 7;
  const int bcol = (bid % nbx) << 7;
  const int kbeg = blockIdx.y * KH;
  float* Cp = blockIdx.y ? P1 : P0;

  f32x4 acc[4][4] = {};

  const int rsub = lane >> 3;
  const int cl = (lane & 7) ^ rsub;
  size_t ga[4], gb[4];
  int la[4];
#pragma unroll
  for (int j = 0; j < 4; ++j) {
    const int r = wave * 32 + j * 8;
    ga[j] = (size_t)(brow + r + rsub) * K + cl * 8 + kbeg;
    gb[j] = (size_t)(bcol + r + rsub) * K + cl * 8 + kbeg;
    la[j] = r * 64;
  }

#define GSTAGE(SA, SB, koff)                                                   \
  do {                                                                         \
    _Pragma("unroll")                                                          \
    for (int jj = 0; jj < 4; ++jj) {                                           \
      __builtin_amdgcn_global_load_lds(                                        \
          (const __attribute__((address_space(1))) uint32_t*)(A + ga[jj] + (koff)), \
          (__attribute__((address_space(3))) uint32_t*)(&SA[la[jj]]), 16, 0, 0);  \
      __builtin_amdgcn_global_load_lds(                                        \
          (const __attribute__((address_space(1))) uint32_t*)(Bt + gb[jj] + (koff)),\
          (__attribute__((address_space(3))) uint32_t*)(&SB[la[jj]]), 16, 0, 0);  \
    }                                                                          \
  } while (0)

#define COMPUTE(SA, SB)                                                        \
  do {                                                                         \
    s16x8 af[4][2], bfr[4][2];                                                 \
    _Pragma("unroll")                                                          \
    for (int m = 0; m < 4; ++m)                                                \
      _Pragma("unroll")                                                        \
      for (int kk = 0; kk < 2; ++kk)                                           \
        af[m][kk] = *(const s16x8*)(&SA[(wr * 64 + m * 16 + fr) * 64 +         \
                                        (((kk * 4 + fg) ^ f7) << 3)]);         \
    _Pragma("unroll")                                                          \
    for (int n = 0; n < 4; ++n)                                                \
      _Pragma("unroll")                                                        \
      for (int kk = 0; kk < 2; ++kk)                                           \
        bfr[n][kk] = *(const s16x8*)(&SB[(wc * 64 + n * 16 + fr) * 64 +        \
                                         (((kk * 4 + fg) ^ f7) << 3)]);        \
    _Pragma("unroll")                                                          \
    for (int kk = 0; kk < 2; ++kk)                                             \
      _Pragma("unroll")                                                        \
      for (int m = 0; m < 4; ++m)                                              \
        _Pragma("unroll")                                                      \
        for (int n = 0; n < 4; ++n)                                            \
          acc[m][n] = __builtin_amdgcn_mfma_f32_16x16x32_bf16(                 \
              af[m][kk], bfr[n][kk], acc[m][n], 0, 0, 0);                      \
  } while (0)

  GSTAGE(sA0, sB0, 0);
  __syncthreads();

  int kt = 0;
  for (;;) {
    if (kt + 64 < KH) {
      GSTAGE(sA1, sB1, kt + 64);
      COMPUTE(sA0, sB0);
      __syncthreads();
    } else {
      COMPUTE(sA0, sB0);
      break;
    }
    kt += 64;
    if (kt + 64 < KH) {
      GSTAGE(sA0, sB0, kt + 64);
      COMPUTE(sA1, sB1);
      __syncthreads();
    } else {
      COMPUTE(sA1, sB1);
      break;
    }
    kt += 64;
  }
#undef GSTAGE
#undef COMPUTE

  const int crow = brow + wr * 64;
  const int ccol = bcol + wc * 64;
#pragma unroll
  for (int m = 0; m < 4; ++m) {
#pragma unroll
    for (int n = 0; n < 4; ++n) {
      const int col = ccol + n * 16 + fr;
#pragma unroll
      for (int j = 0; j < 4; ++j) {
        const int row = crow + m * 16 + fg * 4 + j;
        Cp[(size_t)row * N + col] = acc[m][n][j];
      }
    }
  }
}

// ------------- GEMM v4: 256x256 tile, BK=64, 512 thr, 2-buf counted vmcnt --
// (R10-proven; used for FFN1)
template <int EPI>
__global__ __launch_bounds__(512) void gemm256_bt(
    const bf16* __restrict__ A, const bf16* __restrict__ Bt,
    void* __restrict__ C, const float* __restrict__ bias, int M, int N, int K)
{
  __shared__ bf16 sA0[256 * 64];
  __shared__ bf16 sB0[256 * 64];
  __shared__ bf16 sA1[256 * 64];
  __shared__ bf16 sB1[256 * 64];
  const int tid = threadIdx.x;
  const int wave = tid >> 6, lane = tid & 63;
  const int fr = lane & 15, fg = lane >> 4;
  const int f7 = fr & 7;
  const int wr = wave >> 2, wc = wave & 3;     // 2 x 4 waves, 128x64 out each
  const int nbx = N >> 8;
  int bid = blockIdx.x;
  if ((gridDim.x & 7) == 0) {
    const int cpx = gridDim.x >> 3;
    bid = (bid & 7) * cpx + (bid >> 3);
  }
  const int brow = (bid / nbx) << 8;
  const int bcol = (bid % nbx) << 8;

  f32x4 acc[8][4] = {};

  const int rsub = lane >> 3;
  const int cl = (lane & 7) ^ rsub;
  size_t ga[4], gb[4];
  int la[4];
#pragma unroll
  for (int j = 0; j < 4; ++j) {
    const int r = j * 64 + wave * 8;
    ga[j] = (size_t)(brow + r + rsub) * K + cl * 8;
    gb[j] = (size_t)(bcol + r + rsub) * K + cl * 8;
    la[j] = r * 64;
  }

#define STG6(SA, SB, koff)                                                     \
  do {                                                                         \
    _Pragma("unroll")                                                          \
    for (int jj = 0; jj < 4; ++jj) {                                           \
      __builtin_amdgcn_global_load_lds(                                        \
          (const __attribute__((address_space(1))) uint32_t*)(A + ga[jj] + (koff)), \
          (__attribute__((address_space(3))) uint32_t*)(&SA[la[jj]]), 16, 0, 0);  \
      __builtin_amdgcn_global_load_lds(                                        \
          (const __attribute__((address_space(1))) uint32_t*)(Bt + gb[jj] + (koff)),\
          (__attribute__((address_space(3))) uint32_t*)(&SB[la[jj]]), 16, 0, 0);  \
    }                                                                          \
  } while (0)

#define CMP6(SA, SB)                                                           \
  do {                                                                         \
    s16x8 bfr[4][2];                                                           \
    _Pragma("unroll")                                                          \
    for (int n = 0; n < 4; ++n)                                                \
      _Pragma("unroll")                                                        \
      for (int kk = 0; kk < 2; ++kk)                                           \
        bfr[n][kk] = *(const s16x8*)(&SB[(wc * 64 + n * 16 + fr) * 64 +        \
                                         (((kk * 4 + fg) ^ f7) << 3)]);        \
    __builtin_amdgcn_s_setprio(1);                                             \
    _Pragma("unroll")                                                          \
    for (int m = 0; m < 8; ++m) {                                              \
      s16x8 afm[2];                                                            \
      _Pragma("unroll")                                                        \
      for (int kk = 0; kk < 2; ++kk)                                           \
        afm[kk] = *(const s16x8*)(&SA[(wr * 128 + m * 16 + fr) * 64 +          \
                                      (((kk * 4 + fg) ^ f7) << 3)]);           \
      _Pragma("unroll")                                                        \
      for (int kk = 0; kk < 2; ++kk)                                           \
        _Pragma("unroll")                                                      \
        for (int n = 0; n < 4; ++n)                                            \
          acc[m][n] = __builtin_amdgcn_mfma_f32_16x16x32_bf16(                 \
              afm[kk], bfr[n][kk], acc[m][n], 0, 0, 0);                        \
    }                                                                          \
    __builtin_amdgcn_s_setprio(0);                                             \
  } while (0)

  STG6(sA0, sB0, 0);

  int kt = 0;
  for (;;) {
    if (kt + 64 < K) {
      STG6(sA1, sB1, kt + 64);
      asm volatile("s_waitcnt vmcnt(8)" ::: "memory");
    } else {
      asm volatile("s_waitcnt vmcnt(0)" ::: "memory");
    }
    __builtin_amdgcn_s_barrier();
    __builtin_amdgcn_sched_barrier(0);
    CMP6(sA0, sB0);
    if (kt + 64 >= K) break;
    __builtin_amdgcn_s_barrier();
    __builtin_amdgcn_sched_barrier(0);
    kt += 64;
    if (kt + 64 < K) {
      STG6(sA0, sB0, kt + 64);
      asm volatile("s_waitcnt vmcnt(8)" ::: "memory");
    } else {
      asm volatile("s_waitcnt vmcnt(0)" ::: "memory");
    }
    __builtin_amdgcn_s_barrier();
    __builtin_amdgcn_sched_barrier(0);
    CMP6(sA1, sB1);
    if (kt + 64 >= K) break;
    __builtin_amdgcn_s_barrier();
    __builtin_amdgcn_sched_barrier(0);
    kt += 64;
  }
#undef STG6
#undef CMP6

  const int crow = brow + wr * 128;
  const int ccol = bcol + wc * 64;
#pragma unroll
  for (int m = 0; m < 8; ++m) {
#pragma unroll
    for (int n = 0; n < 4; ++n) {
      const int col = ccol + n * 16 + fr;
#pragma unroll
      for (int j = 0; j < 4; ++j) {
        const int row = crow + m * 16 + fg * 4 + j;
        float v = acc[m][n][j];
        if (EPI == 0) {
          ((bf16*)C)[(size_t)row * N + col] = __float2bfloat16(v);
        } else {
          v += bias[col];
          v = fmaxf(v, 0.f);
          ((bf16*)C)[(size_t)row * N + col] = __float2bfloat16(v);
        }
      }
    }
  }
}

// ------------- flash attention v7: 32 q-rows per wave ------------------------
// LDS-throughput fix: each wave owns TWO 16-row q-sub-tiles and reads the
// K/V fragments from LDS ONCE per k-tile (into registers), reusing them for
// both sub-tiles. Per-CU DS traffic per q-row drops ~32%. Block = 8 waves x
// 32 q-rows = 256 q-rows; grid (8, 32) = 256 blocks = 1/CU. Same 2-buffer
// counted-vmcnt staging, setprio, defer-max as the R12-proven v6.
__global__ __launch_bounds__(512, 2) void attn_fwd(
    const bf16* __restrict__ QK, const bf16* __restrict__ Vt,
    float* __restrict__ Out)
{
  const int LDK = 2048;
  const int qt = blockIdx.x;
  const int bh = blockIdx.y;
  const int b = bh >> 4, h = bh & 15;
  const int tid = threadIdx.x;
  const int wave = tid >> 6, lane = tid & 63;
  const int fr = lane & 15, fg = lane >> 4;
  const int f7 = fr & 7;

  const short* base = (const short*)QK + (size_t)b * 2048 * LDK;
  const short* Qp = base + h * 64;
  const short* Kp = base + 1024 + h * 64;
  const short* Vp = (const short*)Vt + (size_t)h * 64 * 4096 + b * 2048;
  const int q0 = qt * 256 + wave * 32;

  __shared__ short Kbuf0[64 * 64];
  __shared__ short Vbuf0[64 * 64];
  __shared__ short Kbuf1[64 * 64];
  __shared__ short Vbuf1[64 * 64];
  __shared__ short P_lds[8][32 * 72];
  short* Pw = P_lds[wave];

  const int rsub = lane >> 3;
  const int clog = (lane & 7) ^ rsub;
  const short* Ksrc = Kp + (size_t)(8 * wave + rsub) * LDK + clog * 8;
  const short* Vsrc = Vp + (size_t)(8 * wave + rsub) * 4096 + clog * 8;

  // Q fragments for both sub-tiles, pre-scaled by 1/8 (exact in bf16)
  s16x8 qf[2][2];
#pragma unroll
  for (int s = 0; s < 2; ++s) {
    qf[s][0] = *(const s16x8*)(Qp + (size_t)(q0 + s * 16 + fr) * LDK + fg * 8);
    qf[s][1] = *(const s16x8*)(Qp + (size_t)(q0 + s * 16 + fr) * LDK + 32 + fg * 8);
#pragma unroll
    for (int i = 0; i < 8; ++i) {
      qf[s][0][i] = f2bf(bf2f(qf[s][0][i]) * 0.125f);
      qf[s][1][i] = f2bf(bf2f(qf[s][1][i]) * 0.125f);
    }
  }

  f32x4 acc[2][4] = {};
  f32x4 mrow[2], lrow[2] = {};
#pragma unroll
  for (int s = 0; s < 2; ++s)
    mrow[s] = f32x4{-1e30f, -1e30f, -1e30f, -1e30f};

#define STAGE(KB, VB, koff)                                                    \
  do {                                                                         \
    __builtin_amdgcn_global_load_lds(                                          \
        (const __attribute__((address_space(1))) uint32_t*)(Ksrc + (size_t)(koff) * LDK), \
        (__attribute__((address_space(3))) uint32_t*)(&KB[wave * 512]),        \
        16, 0, 0);                                                             \
    __builtin_amdgcn_global_load_lds(                                          \
        (const __attribute__((address_space(1))) uint32_t*)(Vsrc + (koff)),    \
        (__attribute__((address_space(3))) uint32_t*)(&VB[wave * 512]),        \
        16, 0, 0);                                                             \
  } while (0)

#define ATTN_STEP(KB, VB)                                                      \
  do {                                                                         \
    /* K fragments read ONCE, reused by both q-sub-tiles */                    \
    s16x8 kf[4][2];                                                            \
    _Pragma("unroll")                                                          \
    for (int t = 0; t < 4; ++t) {                                              \
      const int ro = (t * 16 + fr) * 64;                                       \
      kf[t][0] = *(const s16x8*)(&KB[ro + ((fg ^ f7) << 3)]);                  \
      kf[t][1] = *(const s16x8*)(&KB[ro + (((4 + fg) ^ f7) << 3)]);            \
    }                                                                          \
    _Pragma("unroll")                                                          \
    for (int s = 0; s < 2; ++s) {                                              \
      f32x4 e[4];                                                              \
      __builtin_amdgcn_s_setprio(1);                                           \
      _Pragma("unroll")                                                        \
      for (int t = 0; t < 4; ++t) {                                            \
        f32x4 z = {};                                                          \
        z = __builtin_amdgcn_mfma_f32_16x16x32_bf16(qf[s][0], kf[t][0], z, 0, 0, 0); \
        z = __builtin_amdgcn_mfma_f32_16x16x32_bf16(qf[s][1], kf[t][1], z, 0, 0, 0); \
        e[t] = z;                                                              \
      }                                                                        \
      __builtin_amdgcn_s_setprio(0);                                           \
      f32x4 lmx;                                                               \
      _Pragma("unroll")                                                        \
      for (int j = 0; j < 4; ++j)                                              \
        lmx[j] = fmaxf(fmaxf(e[0][j], e[1][j]), fmaxf(e[2][j], e[3][j]));      \
      const bool need = (lmx[0] > mrow[s][0] + 8.f) | (lmx[1] > mrow[s][1] + 8.f) | \
                        (lmx[2] > mrow[s][2] + 8.f) | (lmx[3] > mrow[s][3] + 8.f);  \
      if (__any(need)) {                                                       \
        f32x4 mx = lmx;                                                        \
        _Pragma("unroll")                                                      \
        for (int d = 1; d < 16; d <<= 1)                                       \
          _Pragma("unroll")                                                    \
          for (int j = 0; j < 4; ++j) mx[j] = fmaxf(mx[j], __shfl_xor(mx[j], d)); \
        _Pragma("unroll")                                                      \
        for (int j = 0; j < 4; ++j) {                                          \
          const float mn = fmaxf(mrow[s][j], mx[j]);                           \
          const float al = __expf(mrow[s][j] - mn);                            \
          lrow[s][j] *= al;                                                    \
          mrow[s][j] = mn;                                                     \
          _Pragma("unroll")                                                    \
          for (int nn = 0; nn < 4; ++nn) acc[s][nn][j] *= al;                  \
        }                                                                      \
      }                                                                        \
      _Pragma("unroll")                                                        \
      for (int j = 0; j < 4; ++j) {                                            \
        _Pragma("unroll")                                                      \
        for (int t = 0; t < 4; ++t) e[t][j] = __expf(e[t][j] - mrow[s][j]);    \
        lrow[s][j] += (e[0][j] + e[1][j]) + (e[2][j] + e[3][j]);               \
      }                                                                        \
      _Pragma("unroll")                                                        \
      for (int t = 0; t < 4; ++t)                                              \
        _Pragma("unroll")                                                      \
        for (int j = 0; j < 4; ++j)                                            \
          Pw[(s * 16 + fg * 4 + j) * 72 + t * 16 + fr] = f2bf(e[t][j]);        \
    }                                                                          \
    /* V fragments read ONCE, reused by both q-sub-tiles */                    \
    s16x8 vf[4][2];                                                            \
    _Pragma("unroll")                                                          \
    for (int nn = 0; nn < 4; ++nn) {                                           \
      const int ro = (nn * 16 + fr) * 64;                                      \
      vf[nn][0] = *(const s16x8*)(&VB[ro + ((fg ^ f7) << 3)]);                 \
      vf[nn][1] = *(const s16x8*)(&VB[ro + (((4 + fg) ^ f7) << 3)]);           \
    }                                                                          \
    _Pragma("unroll")                                                          \
    for (int s = 0; s < 2; ++s) {                                              \
      const s16x8 pf0 = *(const s16x8*)(Pw + (s * 16 + fr) * 72 + fg * 8);     \
      const s16x8 pf1 = *(const s16x8*)(Pw + (s * 16 + fr) * 72 + 32 + fg * 8);\
      __builtin_amdgcn_s_setprio(1);                                           \
      _Pragma("unroll")                                                        \
      for (int nn = 0; nn < 4; ++nn) {                                         \
        acc[s][nn] = __builtin_amdgcn_mfma_f32_16x16x32_bf16(pf0, vf[nn][0], acc[s][nn], 0, 0, 0); \
        acc[s][nn] = __builtin_amdgcn_mfma_f32_16x16x32_bf16(pf1, vf[nn][1], acc[s][nn], 0, 0, 0); \
      }                                                                        \
      __builtin_amdgcn_s_setprio(0);                                           \
    }                                                                          \
  } while (0)

  STAGE(Kbuf0, Vbuf0, 0);

  for (int kt = 0; kt < 2048; kt += 128) {
    STAGE(Kbuf1, Vbuf1, kt + 64);
    asm volatile("s_waitcnt vmcnt(2)" ::: "memory");
    __builtin_amdgcn_s_barrier();
    __builtin_amdgcn_sched_barrier(0);
    ATTN_STEP(Kbuf0, Vbuf0);
    __builtin_amdgcn_s_barrier();
    __builtin_amdgcn_sched_barrier(0);
    if (kt + 128 < 2048) {
      STAGE(Kbuf0, Vbuf0, kt + 128);
      asm volatile("s_waitcnt vmcnt(2)" ::: "memory");
    } else {
      asm volatile("s_waitcnt vmcnt(0)" ::: "memory");
    }
    __builtin_amdgcn_s_barrier();
    __builtin_amdgcn_sched_barrier(0);
    ATTN_STEP(Kbuf1, Vbuf1);
    __builtin_amdgcn_s_barrier();
    __builtin_amdgcn_sched_barrier(0);
  }
#undef STAGE
#undef ATTN_STEP

#pragma unroll
  for (int s = 0; s < 2; ++s) {
#pragma unroll
    for (int d = 1; d < 16; d <<= 1)
#pragma unroll
      for (int j = 0; j < 4; ++j) lrow[s][j] += __shfl_xor(lrow[s][j], d);
    f32x4 inv;
#pragma unroll
    for (int j = 0; j < 4; ++j) inv[j] = 1.0f / lrow[s][j];
    float* outp = Out + (size_t)(b * 2048 + q0 + s * 16) * 1024 + h * 64;
#pragma unroll
    for (int nn = 0; nn < 4; ++nn)
#pragma unroll
      for (int j = 0; j < 4; ++j)
        outp[(size_t)(fg * 4 + j) * 1024 + nn * 16 + fr] = acc[s][nn][j] * inv[j];
  }
}

// ---------------------------------------------------------------------------
extern "C" void kernel_launch(void* const* d_in, const int* in_sizes, int n_in,
                              void* d_out, int out_size, void* d_ws, size_t ws_size,
                              hipStream_t stream)
{
  const float* x   = (const float*)d_in[0];
  const float* Wq  = (const float*)d_in[1];
  const float* Wk  = (const float*)d_in[2];
  const float* Wv  = (const float*)d_in[3];
  const float* W1  = (const float*)d_in[4];
  const float* b1  = (const float*)d_in[5];
  const float* W2  = (const float*)d_in[6];
  const float* b2  = (const float*)d_in[7];
  const float* g1  = (const float*)d_in[8];
  const float* be1 = (const float*)d_in[9];
  const float* g2  = (const float*)d_in[10];
  const float* be2 = (const float*)d_in[11];
  float* out = (float*)d_out;

  const int M = 4096, D = 1024, DF = 4096;

  bf16* Wqk_t = (bf16*)d_ws;                        // [2048][1024]
  bf16* Wv_t  = Wqk_t + (size_t)2048 * 1024;        // [1024][1024]
  bf16* W1t   = Wv_t + (size_t)1024 * 1024;         // [4096][1024]
  bf16* W2t   = W1t + (size_t)4096 * 1024;          // [1024][4096]
  bf16* big   = W2t + (size_t)4096 * 1024;          // 16M elems = 32MB
  bf16* QK    = big;                                // [4096][2048]
  bf16* Vt    = big + (size_t)8 * 1024 * 1024;      // [1024][4096]
  bf16* hbuf  = big;                                // [4096][4096] (FFN1 out)
  char* p2    = (char*)(big + (size_t)16 * 1024 * 1024);
  bf16* xnorm = (bf16*)p2;                          // [4096][1024]
  float* attnO = (float*)p2;                        // [4096][1024] f32
  float* part0 = (float*)p2;                        // FFN2 split-K partial 0
  char* p3    = p2 + (size_t)M * D * sizeof(float);
  bf16* xres  = (bf16*)p3;                          // [4096][1024]
  bf16* xnorm2 = xres + (size_t)M * D;              // [4096][1024]

  // 1. weight transpose+convert
  transpose_cvt<<<dim3(32, 32), 256, 0, stream>>>(Wq, Wqk_t, D, D);
  transpose_cvt<<<dim3(32, 32), 256, 0, stream>>>(Wk, Wqk_t + (size_t)D * D, D, D);
  transpose_cvt<<<dim3(32, 32), 256, 0, stream>>>(Wv, Wv_t, D, D);
  transpose_cvt<<<dim3(128, 32), 256, 0, stream>>>(W1, W1t, D, DF);
  transpose_cvt<<<dim3(32, 128), 256, 0, stream>>>(W2, W2t, DF, D);
  // 2. LN1
  ln_bf16<<<M, 256, 0, stream>>>(x, g1, be1, xnorm);
  // 3. QK projection (fused Wq|Wk) — R14-proven 128^2 kernel
  gemm_bt<0><<<(M / 128) * (2048 / 128), 256, 0, stream>>>(
      xnorm, Wqk_t, QK, nullptr, nullptr, M, 2048, D);
  // 4. V projection transposed
  gemm_bt<0><<<(D / 128) * (M / 128), 256, 0, stream>>>(
      Wv_t, xnorm, Vt, nullptr, nullptr, D, M, D);
  // 5. attention (32 q-rows/wave, K/V frags register-shared across sub-tiles)
  attn_fwd<<<dim3(8, 32), 512, 0, stream>>>(QK, Vt, attnO);
  // 6. residual + LN2
  add_ln_bf16<<<M, 256, 0, stream>>>(attnO, x, g2, be2, xres, xnorm2);
  // 7. FFN1 (bias + relu fused), 256^2-tile kernel
  gemm256_bt<1><<<(M / 256) * (DF / 256), 512, 0, stream>>>(
      xres, W1t, hbuf, b1, M, DF, D);
  // 8. FFN2 split-K=2 (grid 512 = 2 blocks/CU): partials -> part0, out
  gemm_splitk<<<dim3((M / 128) * (D / 128), 2), 256, 0, stream>>>(
      hbuf, W2t, part0, out, M, D, DF, DF / 2);
  // 9. FFN2 epilogue: out = part0 + out + bias + xnorm2
  ffn2_epi<<<M, 256, 0, stream>>>(part0, out, b2, xnorm2);
}

// Round 17
// 221.999 us; speedup vs baseline: 1.0542x; 1.0542x over previous
//
#include <hip/hip_runtime.h>
#include <hip/hip_bf16.h>
#include <stdint.h>

typedef __hip_bfloat16 bf16;
typedef __attribute__((ext_vector_type(4))) float f32x4;
typedef __attribute__((ext_vector_type(8))) short s16x8;
typedef __attribute__((ext_vector_type(4))) short s16x4;

#define DEV static __device__ __forceinline__

DEV short f2bf(float f) {
  bf16 h = __float2bfloat16(f);
  short s;
  __builtin_memcpy(&s, &h, 2);
  return s;
}
DEV float bf2f(short s) {
  bf16 h;
  __builtin_memcpy(&h, &s, 2);
  return __bfloat162float(h);
}

// ------------- transpose + f32->bf16 convert: W[K][N] -> Wt[N][K] ----------
__global__ __launch_bounds__(256) void transpose_cvt(
    const float* __restrict__ W, bf16* __restrict__ Wt, int K, int N)
{
  __shared__ float tile[32][33];
  const int n0 = blockIdx.x << 5;
  const int k0 = blockIdx.y << 5;
  const int tx = threadIdx.x & 31, ty = threadIdx.x >> 5;
#pragma unroll
  for (int i = 0; i < 4; ++i)
    tile[ty + i * 8][tx] = W[(size_t)(k0 + ty + i * 8) * N + n0 + tx];
  __syncthreads();
#pragma unroll
  for (int i = 0; i < 4; ++i)
    Wt[(size_t)(n0 + ty + i * 8) * K + k0 + tx] = __float2bfloat16(tile[tx][ty + i * 8]);
}

// ------------- fused 3x 1024x1024 transpose (Wq, Wk, Wv) -------------------
__global__ __launch_bounds__(256) void transpose_cvt3(
    const float* __restrict__ Wq, const float* __restrict__ Wk,
    const float* __restrict__ Wv, bf16* __restrict__ Wqk_t,
    bf16* __restrict__ Wv_t)
{
  const float* W = (blockIdx.z == 0) ? Wq : (blockIdx.z == 1) ? Wk : Wv;
  bf16* Wt = (blockIdx.z == 0) ? Wqk_t
           : (blockIdx.z == 1) ? (Wqk_t + (size_t)1024 * 1024) : Wv_t;
  __shared__ float tile[32][33];
  const int n0 = blockIdx.x << 5;
  const int k0 = blockIdx.y << 5;
  const int tx = threadIdx.x & 31, ty = threadIdx.x >> 5;
#pragma unroll
  for (int i = 0; i < 4; ++i)
    tile[ty + i * 8][tx] = W[(size_t)(k0 + ty + i * 8) * 1024 + n0 + tx];
  __syncthreads();
#pragma unroll
  for (int i = 0; i < 4; ++i)
    Wt[(size_t)(n0 + ty + i * 8) * 1024 + k0 + tx] = __float2bfloat16(tile[tx][ty + i * 8]);
}

// ------------- layernorm (f32 in, bf16 out), D = 1024 ---------------------
__global__ __launch_bounds__(256) void ln_bf16(
    const float* __restrict__ x, const float* __restrict__ g,
    const float* __restrict__ be, bf16* __restrict__ out)
{
  const int t = threadIdx.x;
  const size_t row = blockIdx.x;
  const float4 v = ((const float4*)(x + row * 1024))[t];
  float s = v.x + v.y + v.z + v.w;
  float ss = v.x * v.x + v.y * v.y + v.z * v.z + v.w * v.w;
#pragma unroll
  for (int off = 32; off > 0; off >>= 1) {
    s += __shfl_down(s, off);
    ss += __shfl_down(ss, off);
  }
  __shared__ float sh[8];
  const int wave = t >> 6, lane = t & 63;
  if (!lane) { sh[wave] = s; sh[4 + wave] = ss; }
  __syncthreads();
  s = sh[0] + sh[1] + sh[2] + sh[3];
  ss = sh[4] + sh[5] + sh[6] + sh[7];
  const float mean = s * (1.f / 1024.f);
  const float rstd = rsqrtf(ss * (1.f / 1024.f) - mean * mean + 1e-5f);
  const float4 gv = ((const float4*)g)[t];
  const float4 bv = ((const float4*)be)[t];
  s16x4 o;
  o[0] = f2bf((v.x - mean) * rstd * gv.x + bv.x);
  o[1] = f2bf((v.y - mean) * rstd * gv.y + bv.y);
  o[2] = f2bf((v.z - mean) * rstd * gv.z + bv.z);
  o[3] = f2bf((v.w - mean) * rstd * gv.w + bv.w);
  ((s16x4*)(out + row * 1024))[t] = o;
}

// ------------- residual add + layernorm ------------------------------------
__global__ __launch_bounds__(256) void add_ln_bf16(
    const float* __restrict__ a, const float* __restrict__ x,
    const float* __restrict__ g, const float* __restrict__ be,
    bf16* __restrict__ xres, bf16* __restrict__ xnorm)
{
  const int t = threadIdx.x;
  const size_t row = blockIdx.x;
  const float4 av = ((const float4*)(a + row * 1024))[t];
  const float4 xv = ((const float4*)(x + row * 1024))[t];
  float4 v;
  v.x = av.x + xv.x; v.y = av.y + xv.y; v.z = av.z + xv.z; v.w = av.w + xv.w;
  float s = v.x + v.y + v.z + v.w;
  float ss = v.x * v.x + v.y * v.y + v.z * v.z + v.w * v.w;
#pragma unroll
  for (int off = 32; off > 0; off >>= 1) {
    s += __shfl_down(s, off);
    ss += __shfl_down(ss, off);
  }
  __shared__ float sh[8];
  const int wave = t >> 6, lane = t & 63;
  if (!lane) { sh[wave] = s; sh[4 + wave] = ss; }
  __syncthreads();
  s = sh[0] + sh[1] + sh[2] + sh[3];
  ss = sh[4] + sh[5] + sh[6] + sh[7];
  const float mean = s * (1.f / 1024.f);
  const float rstd = rsqrtf(ss * (1.f / 1024.f) - mean * mean + 1e-5f);
  const float4 gv = ((const float4*)g)[t];
  const float4 bv = ((const float4*)be)[t];
  s16x4 r, o;
  r[0] = f2bf(v.x); r[1] = f2bf(v.y); r[2] = f2bf(v.z); r[3] = f2bf(v.w);
  o[0] = f2bf((v.x - mean) * rstd * gv.x + bv.x);
  o[1] = f2bf((v.y - mean) * rstd * gv.y + bv.y);
  o[2] = f2bf((v.z - mean) * rstd * gv.z + bv.z);
  o[3] = f2bf((v.w - mean) * rstd * gv.w + bv.w);
  ((s16x4*)(xres + row * 1024))[t] = r;
  ((s16x4*)(xnorm + row * 1024))[t] = o;
}

// ------------- FFN2 epilogue: out = p0 + out + bias + xnorm2 ---------------
__global__ __launch_bounds__(256) void ffn2_epi(
    const float* __restrict__ p0, float* __restrict__ out,
    const float* __restrict__ bias, const bf16* __restrict__ xn2)
{
  const int t = threadIdx.x;
  const size_t row = blockIdx.x;
  const float4 a = ((const float4*)(p0 + row * 1024))[t];
  const float4 b = ((const float4*)(out + row * 1024))[t];
  const float4 bv = ((const float4*)bias)[t];
  const s16x4 xv = ((const s16x4*)(xn2 + row * 1024))[t];
  float4 o;
  o.x = a.x + b.x + bv.x + bf2f(xv[0]);
  o.y = a.y + b.y + bv.y + bf2f(xv[1]);
  o.z = a.z + b.z + bv.z + bf2f(xv[2]);
  o.w = a.w + b.w + bv.w + bf2f(xv[3]);
  ((float4*)(out + row * 1024))[t] = o;
}

// ------------- GEMM v2: 128x128, BK=64, 2-phase dbuf, __syncthreads --------
// (R7/R10-proven structure — used for QKV, Vt)
template <int EPI>
__global__ __launch_bounds__(256) void gemm_bt(
    const bf16* __restrict__ A, const bf16* __restrict__ Bt,
    void* __restrict__ C, const float* __restrict__ bias,
    const bf16* __restrict__ add_bf16, int M, int N, int K)
{
  __shared__ bf16 sA0[128 * 64];
  __shared__ bf16 sB0[128 * 64];
  __shared__ bf16 sA1[128 * 64];
  __shared__ bf16 sB1[128 * 64];
  const int tid = threadIdx.x;
  const int wave = tid >> 6, lane = tid & 63;
  const int fr = lane & 15, fg = lane >> 4;
  const int f7 = fr & 7;
  const int wr = wave >> 1, wc = wave & 1;
  const int nbx = N >> 7;
  int bid = blockIdx.x;
  if ((gridDim.x & 7) == 0) {
    const int cpx = gridDim.x >> 3;
    bid = (bid & 7) * cpx + (bid >> 3);
  }
  const int brow = (bid / nbx) << 7;
  const int bcol = (bid % nbx) << 7;

  f32x4 acc[4][4] = {};

  const int rsub = lane >> 3;
  const int cl = (lane & 7) ^ rsub;
  size_t ga[4], gb[4];
  int la[4];
#pragma unroll
  for (int j = 0; j < 4; ++j) {
    const int r = wave * 32 + j * 8;
    ga[j] = (size_t)(brow + r + rsub) * K + cl * 8;
    gb[j] = (size_t)(bcol + r + rsub) * K + cl * 8;
    la[j] = r * 64;
  }

#define GSTAGE(SA, SB, koff)                                                   \
  do {                                                                         \
    _Pragma("unroll")                                                          \
    for (int jj = 0; jj < 4; ++jj) {                                           \
      __builtin_amdgcn_global_load_lds(                                        \
          (const __attribute__((address_space(1))) uint32_t*)(A + ga[jj] + (koff)), \
          (__attribute__((address_space(3))) uint32_t*)(&SA[la[jj]]), 16, 0, 0);  \
      __builtin_amdgcn_global_load_lds(                                        \
          (const __attribute__((address_space(1))) uint32_t*)(Bt + gb[jj] + (koff)),\
          (__attribute__((address_space(3))) uint32_t*)(&SB[la[jj]]), 16, 0, 0);  \
    }                                                                          \
  } while (0)

#define COMPUTE(SA, SB)                                                        \
  do {                                                                         \
    s16x8 af[4][2], bfr[4][2];                                                 \
    _Pragma("unroll")                                                          \
    for (int m = 0; m < 4; ++m)                                                \
      _Pragma("unroll")                                                        \
      for (int kk = 0; kk < 2; ++kk)                                           \
        af[m][kk] = *(const s16x8*)(&SA[(wr * 64 + m * 16 + fr) * 64 +         \
                                        (((kk * 4 + fg) ^ f7) << 3)]);         \
    _Pragma("unroll")                                                          \
    for (int n = 0; n < 4; ++n)                                                \
      _Pragma("unroll")                                                        \
      for (int kk = 0; kk < 2; ++kk)                                           \
        bfr[n][kk] = *(const s16x8*)(&SB[(wc * 64 + n * 16 + fr) * 64 +        \
                                         (((kk * 4 + fg) ^ f7) << 3)]);        \
    _Pragma("unroll")                                                          \
    for (int kk = 0; kk < 2; ++kk)                                             \
      _Pragma("unroll")                                                        \
      for (int m = 0; m < 4; ++m)                                              \
        _Pragma("unroll")                                                      \
        for (int n = 0; n < 4; ++n)                                            \
          acc[m][n] = __builtin_amdgcn_mfma_f32_16x16x32_bf16(                 \
              af[m][kk], bfr[n][kk], acc[m][n], 0, 0, 0);                      \
  } while (0)

  GSTAGE(sA0, sB0, 0);
  __syncthreads();

  int kt = 0;
  for (;;) {
    if (kt + 64 < K) {
      GSTAGE(sA1, sB1, kt + 64);
      COMPUTE(sA0, sB0);
      __syncthreads();
    } else {
      COMPUTE(sA0, sB0);
      break;
    }
    kt += 64;
    if (kt + 64 < K) {
      GSTAGE(sA0, sB0, kt + 64);
      COMPUTE(sA1, sB1);
      __syncthreads();
    } else {
      COMPUTE(sA1, sB1);
      break;
    }
    kt += 64;
  }
#undef GSTAGE
#undef COMPUTE

  const int crow = brow + wr * 64;
  const int ccol = bcol + wc * 64;
#pragma unroll
  for (int m = 0; m < 4; ++m) {
#pragma unroll
    for (int n = 0; n < 4; ++n) {
      const int col = ccol + n * 16 + fr;
#pragma unroll
      for (int j = 0; j < 4; ++j) {
        const int row = crow + m * 16 + fg * 4 + j;
        float v = acc[m][n][j];
        if (EPI == 0) {
          ((bf16*)C)[(size_t)row * N + col] = __float2bfloat16(v);
        } else if (EPI == 1) {
          v += bias[col];
          v = fmaxf(v, 0.f);
          ((bf16*)C)[(size_t)row * N + col] = __float2bfloat16(v);
        } else {
          float a;
          {
            bf16 hb = add_bf16[(size_t)row * N + col];
            a = __bfloat162float(hb);
          }
          ((float*)C)[(size_t)row * N + col] = v + bias[col] + a;
        }
      }
    }
  }
}

// ------------- GEMM split-K: 128x128 tile, K-half per blockIdx.y -----------
// (R14-proven; used for FFN2)
__global__ __launch_bounds__(256) void gemm_splitk(
    const bf16* __restrict__ A, const bf16* __restrict__ Bt,
    float* __restrict__ P0, float* __restrict__ P1, int M, int N, int K, int KH)
{
  __shared__ bf16 sA0[128 * 64];
  __shared__ bf16 sB0[128 * 64];
  __shared__ bf16 sA1[128 * 64];
  __shared__ bf16 sB1[128 * 64];
  const int tid = threadIdx.x;
  const int wave = tid >> 6, lane = tid & 63;
  const int fr = lane & 15, fg = lane >> 4;
  const int f7 = fr & 7;
  const int wr = wave >> 1, wc = wave & 1;
  const int nbx = N >> 7;
  int bid = blockIdx.x;
  if ((gridDim.x & 7) == 0) {
    const int cpx = gridDim.x >> 3;
    bid = (bid & 7) * cpx + (bid >> 3);
  }
  const int brow = (bid / nbx) << 7;
  const int bcol = (bid % nbx) << 7;
  const int kbeg = blockIdx.y * KH;
  float* Cp = blockIdx.y ? P1 : P0;

  f32x4 acc[4][4] = {};

  const int rsub = lane >> 3;
  const int cl = (lane & 7) ^ rsub;
  size_t ga[4], gb[4];
  int la[4];
#pragma unroll
  for (int j = 0; j < 4; ++j) {
    const int r = wave * 32 + j * 8;
    ga[j] = (size_t)(brow + r + rsub) * K + cl * 8 + kbeg;
    gb[j] = (size_t)(bcol + r + rsub) * K + cl * 8 + kbeg;
    la[j] = r * 64;
  }

#define GSTAGE(SA, SB, koff)                                                   \
  do {                                                                         \
    _Pragma("unroll")                                                          \
    for (int jj = 0; jj < 4; ++jj) {                                           \
      __builtin_amdgcn_global_load_lds(                                        \
          (const __attribute__((address_space(1))) uint32_t*)(A + ga[jj] + (koff)), \
          (__attribute__((address_space(3))) uint32_t*)(&SA[la[jj]]), 16, 0, 0);  \
      __builtin_amdgcn_global_load_lds(                                        \
          (const __attribute__((address_space(1))) uint32_t*)(Bt + gb[jj] + (koff)),\
          (__attribute__((address_space(3))) uint32_t*)(&SB[la[jj]]), 16, 0, 0);  \
    }                                                                          \
  } while (0)

#define COMPUTE(SA, SB)                                                        \
  do {                                                                         \
    s16x8 af[4][2], bfr[4][2];                                                 \
    _Pragma("unroll")                                                          \
    for (int m = 0; m < 4; ++m)                                                \
      _Pragma("unroll")                                                        \
      for (int kk = 0; kk < 2; ++kk)                                           \
        af[m][kk] = *(const s16x8*)(&SA[(wr * 64 + m * 16 + fr) * 64 +         \
                                        (((kk * 4 + fg) ^ f7) << 3)]);         \
    _Pragma("unroll")                                                          \
    for (int n = 0; n < 4; ++n)                                                \
      _Pragma("unroll")                                                        \
      for (int kk = 0; kk < 2; ++kk)                                           \
        bfr[n][kk] = *(const s16x8*)(&SB[(wc * 64 + n * 16 + fr) * 64 +        \
                                         (((kk * 4 + fg) ^ f7) << 3)]);        \
    _Pragma("unroll")                                                          \
    for (int kk = 0; kk < 2; ++kk)                                             \
      _Pragma("unroll")                                                        \
      for (int m = 0; m < 4; ++m)                                              \
        _Pragma("unroll")                                                      \
        for (int n = 0; n < 4; ++n)                                            \
          acc[m][n] = __builtin_amdgcn_mfma_f32_16x16x32_bf16(                 \
              af[m][kk], bfr[n][kk], acc[m][n], 0, 0, 0);                      \
  } while (0)

  GSTAGE(sA0, sB0, 0);
  __syncthreads();

  int kt = 0;
  for (;;) {
    if (kt + 64 < KH) {
      GSTAGE(sA1, sB1, kt + 64);
      COMPUTE(sA0, sB0);
      __syncthreads();
    } else {
      COMPUTE(sA0, sB0);
      break;
    }
    kt += 64;
    if (kt + 64 < KH) {
      GSTAGE(sA0, sB0, kt + 64);
      COMPUTE(sA1, sB1);
      __syncthreads();
    } else {
      COMPUTE(sA1, sB1);
      break;
    }
    kt += 64;
  }
#undef GSTAGE
#undef COMPUTE

  const int crow = brow + wr * 64;
  const int ccol = bcol + wc * 64;
#pragma unroll
  for (int m = 0; m < 4; ++m) {
#pragma unroll
    for (int n = 0; n < 4; ++n) {
      const int col = ccol + n * 16 + fr;
#pragma unroll
      for (int j = 0; j < 4; ++j) {
        const int row = crow + m * 16 + fg * 4 + j;
        Cp[(size_t)row * N + col] = acc[m][n][j];
      }
    }
  }
}

// ------------- GEMM v4: 256x256 tile, BK=64, 512 thr, 2-buf counted vmcnt --
// (R10-proven; used for FFN1)
template <int EPI>
__global__ __launch_bounds__(512) void gemm256_bt(
    const bf16* __restrict__ A, const bf16* __restrict__ Bt,
    void* __restrict__ C, const float* __restrict__ bias, int M, int N, int K)
{
  __shared__ bf16 sA0[256 * 64];
  __shared__ bf16 sB0[256 * 64];
  __shared__ bf16 sA1[256 * 64];
  __shared__ bf16 sB1[256 * 64];
  const int tid = threadIdx.x;
  const int wave = tid >> 6, lane = tid & 63;
  const int fr = lane & 15, fg = lane >> 4;
  const int f7 = fr & 7;
  const int wr = wave >> 2, wc = wave & 3;     // 2 x 4 waves, 128x64 out each
  const int nbx = N >> 8;
  int bid = blockIdx.x;
  if ((gridDim.x & 7) == 0) {
    const int cpx = gridDim.x >> 3;
    bid = (bid & 7) * cpx + (bid >> 3);
  }
  const int brow = (bid / nbx) << 8;
  const int bcol = (bid % nbx) << 8;

  f32x4 acc[8][4] = {};

  const int rsub = lane >> 3;
  const int cl = (lane & 7) ^ rsub;
  size_t ga[4], gb[4];
  int la[4];
#pragma unroll
  for (int j = 0; j < 4; ++j) {
    const int r = j * 64 + wave * 8;
    ga[j] = (size_t)(brow + r + rsub) * K + cl * 8;
    gb[j] = (size_t)(bcol + r + rsub) * K + cl * 8;
    la[j] = r * 64;
  }

#define STG6(SA, SB, koff)                                                     \
  do {                                                                         \
    _Pragma("unroll")                                                          \
    for (int jj = 0; jj < 4; ++jj) {                                           \
      __builtin_amdgcn_global_load_lds(                                        \
          (const __attribute__((address_space(1))) uint32_t*)(A + ga[jj] + (koff)), \
          (__attribute__((address_space(3))) uint32_t*)(&SA[la[jj]]), 16, 0, 0);  \
      __builtin_amdgcn_global_load_lds(                                        \
          (const __attribute__((address_space(1))) uint32_t*)(Bt + gb[jj] + (koff)),\
          (__attribute__((address_space(3))) uint32_t*)(&SB[la[jj]]), 16, 0, 0);  \
    }                                                                          \
  } while (0)

#define CMP6(SA, SB)                                                           \
  do {                                                                         \
    s16x8 bfr[4][2];                                                           \
    _Pragma("unroll")                                                          \
    for (int n = 0; n < 4; ++n)                                                \
      _Pragma("unroll")                                                        \
      for (int kk = 0; kk < 2; ++kk)                                           \
        bfr[n][kk] = *(const s16x8*)(&SB[(wc * 64 + n * 16 + fr) * 64 +        \
                                         (((kk * 4 + fg) ^ f7) << 3)]);        \
    __builtin_amdgcn_s_setprio(1);                                             \
    _Pragma("unroll")                                                          \
    for (int m = 0; m < 8; ++m) {                                              \
      s16x8 afm[2];                                                            \
      _Pragma("unroll")                                                        \
      for (int kk = 0; kk < 2; ++kk)                                           \
        afm[kk] = *(const s16x8*)(&SA[(wr * 128 + m * 16 + fr) * 64 +          \
                                      (((kk * 4 + fg) ^ f7) << 3)]);           \
      _Pragma("unroll")                                                        \
      for (int kk = 0; kk < 2; ++kk)                                           \
        _Pragma("unroll")                                                      \
        for (int n = 0; n < 4; ++n)                                            \
          acc[m][n] = __builtin_amdgcn_mfma_f32_16x16x32_bf16(                 \
              afm[kk], bfr[n][kk], acc[m][n], 0, 0, 0);                        \
    }                                                                          \
    __builtin_amdgcn_s_setprio(0);                                             \
  } while (0)

  STG6(sA0, sB0, 0);

  int kt = 0;
  for (;;) {
    if (kt + 64 < K) {
      STG6(sA1, sB1, kt + 64);
      asm volatile("s_waitcnt vmcnt(8)" ::: "memory");
    } else {
      asm volatile("s_waitcnt vmcnt(0)" ::: "memory");
    }
    __builtin_amdgcn_s_barrier();
    __builtin_amdgcn_sched_barrier(0);
    CMP6(sA0, sB0);
    if (kt + 64 >= K) break;
    __builtin_amdgcn_s_barrier();
    __builtin_amdgcn_sched_barrier(0);
    kt += 64;
    if (kt + 64 < K) {
      STG6(sA0, sB0, kt + 64);
      asm volatile("s_waitcnt vmcnt(8)" ::: "memory");
    } else {
      asm volatile("s_waitcnt vmcnt(0)" ::: "memory");
    }
    __builtin_amdgcn_s_barrier();
    __builtin_amdgcn_sched_barrier(0);
    CMP6(sA1, sB1);
    if (kt + 64 >= K) break;
    __builtin_amdgcn_s_barrier();
    __builtin_amdgcn_sched_barrier(0);
    kt += 64;
  }
#undef STG6
#undef CMP6

  const int crow = brow + wr * 128;
  const int ccol = bcol + wc * 64;
#pragma unroll
  for (int m = 0; m < 8; ++m) {
#pragma unroll
    for (int n = 0; n < 4; ++n) {
      const int col = ccol + n * 16 + fr;
#pragma unroll
      for (int j = 0; j < 4; ++j) {
        const int row = crow + m * 16 + fg * 4 + j;
        float v = acc[m][n][j];
        if (EPI == 0) {
          ((bf16*)C)[(size_t)row * N + col] = __float2bfloat16(v);
        } else {
          v += bias[col];
          v = fmaxf(v, 0.f);
          ((bf16*)C)[(size_t)row * N + col] = __float2bfloat16(v);
        }
      }
    }
  }
}

// ------------- flash attention v6 (R12-proven, best: 68 us) -----------------
__global__ __launch_bounds__(512, 4) void attn_fwd(
    const bf16* __restrict__ QK, const bf16* __restrict__ Vt,
    float* __restrict__ Out)
{
  const int LDK = 2048;
  const int qt = blockIdx.x;
  const int bh = blockIdx.y;
  const int b = bh >> 4, h = bh & 15;
  const int tid = threadIdx.x;
  const int wave = tid >> 6, lane = tid & 63;
  const int fr = lane & 15, fg = lane >> 4;
  const int f7 = fr & 7;

  const short* base = (const short*)QK + (size_t)b * 2048 * LDK;
  const short* Qp = base + h * 64;
  const short* Kp = base + 1024 + h * 64;
  const short* Vp = (const short*)Vt + (size_t)h * 64 * 4096 + b * 2048;
  const int q0 = qt * 128 + wave * 16;

  __shared__ short Kbuf0[64 * 64];
  __shared__ short Vbuf0[64 * 64];
  __shared__ short Kbuf1[64 * 64];
  __shared__ short Vbuf1[64 * 64];
  __shared__ short P_lds[8][16 * 72];
  short* Pw = P_lds[wave];

  const int rsub = lane >> 3;
  const int clog = (lane & 7) ^ rsub;
  const short* Ksrc = Kp + (size_t)(8 * wave + rsub) * LDK + clog * 8;
  const short* Vsrc = Vp + (size_t)(8 * wave + rsub) * 4096 + clog * 8;

  s16x8 qf0 = *(const s16x8*)(Qp + (size_t)(q0 + fr) * LDK + fg * 8);
  s16x8 qf1 = *(const s16x8*)(Qp + (size_t)(q0 + fr) * LDK + 32 + fg * 8);
#pragma unroll
  for (int i = 0; i < 8; ++i) {
    qf0[i] = f2bf(bf2f(qf0[i]) * 0.125f);
    qf1[i] = f2bf(bf2f(qf1[i]) * 0.125f);
  }

  f32x4 acc[4] = {};
  f32x4 mrow = {-1e30f, -1e30f, -1e30f, -1e30f};
  f32x4 lrow = {};

#define STAGE(KB, VB, koff)                                                    \
  do {                                                                         \
    __builtin_amdgcn_global_load_lds(                                          \
        (const __attribute__((address_space(1))) uint32_t*)(Ksrc + (size_t)(koff) * LDK), \
        (__attribute__((address_space(3))) uint32_t*)(&KB[wave * 512]),        \
        16, 0, 0);                                                             \
    __builtin_amdgcn_global_load_lds(                                          \
        (const __attribute__((address_space(1))) uint32_t*)(Vsrc + (koff)),    \
        (__attribute__((address_space(3))) uint32_t*)(&VB[wave * 512]),        \
        16, 0, 0);                                                             \
  } while (0)

#define ATTN_STEP(KB, VB)                                                      \
  do {                                                                         \
    f32x4 e[4];                                                                \
    __builtin_amdgcn_s_setprio(1);                                             \
    _Pragma("unroll")                                                          \
    for (int t = 0; t < 4; ++t) {                                              \
      const int ro = (t * 16 + fr) * 64;                                       \
      const s16x8 k0 = *(const s16x8*)(&KB[ro + ((fg ^ f7) << 3)]);            \
      const s16x8 k1 = *(const s16x8*)(&KB[ro + (((4 + fg) ^ f7) << 3)]);      \
      f32x4 z = {};                                                            \
      z = __builtin_amdgcn_mfma_f32_16x16x32_bf16(qf0, k0, z, 0, 0, 0);        \
      z = __builtin_amdgcn_mfma_f32_16x16x32_bf16(qf1, k1, z, 0, 0, 0);        \
      e[t] = z;                                                                \
    }                                                                          \
    __builtin_amdgcn_s_setprio(0);                                             \
    f32x4 lmx;                                                                 \
    _Pragma("unroll")                                                          \
    for (int j = 0; j < 4; ++j)                                                \
      lmx[j] = fmaxf(fmaxf(e[0][j], e[1][j]), fmaxf(e[2][j], e[3][j]));        \
    const bool need = (lmx[0] > mrow[0] + 8.f) | (lmx[1] > mrow[1] + 8.f) |    \
                      (lmx[2] > mrow[2] + 8.f) | (lmx[3] > mrow[3] + 8.f);     \
    if (__any(need)) {                                                         \
      f32x4 mx = lmx;                                                          \
      _Pragma("unroll")                                                        \
      for (int d = 1; d < 16; d <<= 1)                                         \
        _Pragma("unroll")                                                      \
        for (int j = 0; j < 4; ++j) mx[j] = fmaxf(mx[j], __shfl_xor(mx[j], d));\
      _Pragma("unroll")                                                        \
      for (int j = 0; j < 4; ++j) {                                            \
        const float mn = fmaxf(mrow[j], mx[j]);                                \
        const float al = __expf(mrow[j] - mn);                                 \
        lrow[j] *= al;                                                         \
        mrow[j] = mn;                                                          \
        _Pragma("unroll")                                                      \
        for (int nn = 0; nn < 4; ++nn) acc[nn][j] *= al;                       \
      }                                                                        \
    }                                                                          \
    _Pragma("unroll")                                                          \
    for (int j = 0; j < 4; ++j) {                                              \
      _Pragma("unroll")                                                        \
      for (int t = 0; t < 4; ++t) e[t][j] = __expf(e[t][j] - mrow[j]);         \
      lrow[j] += (e[0][j] + e[1][j]) + (e[2][j] + e[3][j]);                    \
    }                                                                          \
    _Pragma("unroll")                                                          \
    for (int t = 0; t < 4; ++t)                                                \
      _Pragma("unroll")                                                        \
      for (int j = 0; j < 4; ++j)                                              \
        Pw[(fg * 4 + j) * 72 + t * 16 + fr] = f2bf(e[t][j]);                   \
    const s16x8 pf0 = *(const s16x8*)(Pw + fr * 72 + fg * 8);                  \
    const s16x8 pf1 = *(const s16x8*)(Pw + fr * 72 + 32 + fg * 8);             \
    __builtin_amdgcn_s_setprio(1);                                             \
    _Pragma("unroll")                                                          \
    for (int nn = 0; nn < 4; ++nn) {                                           \
      const int ro = (nn * 16 + fr) * 64;                                      \
      const s16x8 vf0 = *(const s16x8*)(&VB[ro + ((fg ^ f7) << 3)]);           \
      const s16x8 vf1 = *(const s16x8*)(&VB[ro + (((4 + fg) ^ f7) << 3)]);     \
      acc[nn] = __builtin_amdgcn_mfma_f32_16x16x32_bf16(pf0, vf0, acc[nn], 0, 0, 0); \
      acc[nn] = __builtin_amdgcn_mfma_f32_16x16x32_bf16(pf1, vf1, acc[nn], 0, 0, 0); \
    }                                                                          \
    __builtin_amdgcn_s_setprio(0);                                             \
  } while (0)

  STAGE(Kbuf0, Vbuf0, 0);

  for (int kt = 0; kt < 2048; kt += 128) {
    STAGE(Kbuf1, Vbuf1, kt + 64);
    asm volatile("s_waitcnt vmcnt(2)" ::: "memory");
    __builtin_amdgcn_s_barrier();
    __builtin_amdgcn_sched_barrier(0);
    ATTN_STEP(Kbuf0, Vbuf0);
    __builtin_amdgcn_s_barrier();
    __builtin_amdgcn_sched_barrier(0);
    if (kt + 128 < 2048) {
      STAGE(Kbuf0, Vbuf0, kt + 128);
      asm volatile("s_waitcnt vmcnt(2)" ::: "memory");
    } else {
      asm volatile("s_waitcnt vmcnt(0)" ::: "memory");
    }
    __builtin_amdgcn_s_barrier();
    __builtin_amdgcn_sched_barrier(0);
    ATTN_STEP(Kbuf1, Vbuf1);
    __builtin_amdgcn_s_barrier();
    __builtin_amdgcn_sched_barrier(0);
  }
#undef STAGE
#undef ATTN_STEP

#pragma unroll
  for (int d = 1; d < 16; d <<= 1)
#pragma unroll
    for (int j = 0; j < 4; ++j) lrow[j] += __shfl_xor(lrow[j], d);
  f32x4 inv;
#pragma unroll
  for (int j = 0; j < 4; ++j) inv[j] = 1.0f / lrow[j];
  float* outp = Out + (size_t)(b * 2048 + q0) * 1024 + h * 64;
#pragma unroll
  for (int nn = 0; nn < 4; ++nn)
#pragma unroll
    for (int j = 0; j < 4; ++j)
      outp[(size_t)(fg * 4 + j) * 1024 + nn * 16 + fr] = acc[nn][j] * inv[j];
}

// ---------------------------------------------------------------------------
extern "C" void kernel_launch(void* const* d_in, const int* in_sizes, int n_in,
                              void* d_out, int out_size, void* d_ws, size_t ws_size,
                              hipStream_t stream)
{
  const float* x   = (const float*)d_in[0];
  const float* Wq  = (const float*)d_in[1];
  const float* Wk  = (const float*)d_in[2];
  const float* Wv  = (const float*)d_in[3];
  const float* W1  = (const float*)d_in[4];
  const float* b1  = (const float*)d_in[5];
  const float* W2  = (const float*)d_in[6];
  const float* b2  = (const float*)d_in[7];
  const float* g1  = (const float*)d_in[8];
  const float* be1 = (const float*)d_in[9];
  const float* g2  = (const float*)d_in[10];
  const float* be2 = (const float*)d_in[11];
  float* out = (float*)d_out;

  const int M = 4096, D = 1024, DF = 4096;

  bf16* Wqk_t = (bf16*)d_ws;                        // [2048][1024]
  bf16* Wv_t  = Wqk_t + (size_t)2048 * 1024;        // [1024][1024]
  bf16* W1t   = Wv_t + (size_t)1024 * 1024;         // [4096][1024]
  bf16* W2t   = W1t + (size_t)4096 * 1024;          // [1024][4096]
  bf16* big   = W2t + (size_t)4096 * 1024;          // 16M elems = 32MB
  bf16* QK    = big;                                // [4096][2048]
  bf16* Vt    = big + (size_t)8 * 1024 * 1024;      // [1024][4096]
  bf16* hbuf  = big;                                // [4096][4096] (FFN1 out)
  char* p2    = (char*)(big + (size_t)16 * 1024 * 1024);
  bf16* xnorm = (bf16*)p2;                          // [4096][1024]
  float* attnO = (float*)p2;                        // [4096][1024] f32
  float* part0 = (float*)p2;                        // FFN2 split-K partial 0
  char* p3    = p2 + (size_t)M * D * sizeof(float);
  bf16* xres  = (bf16*)p3;                          // [4096][1024]
  bf16* xnorm2 = xres + (size_t)M * D;              // [4096][1024]

  // 1. weight transpose+convert (Wq/Wk/Wv fused into one launch)
  transpose_cvt3<<<dim3(32, 32, 3), 256, 0, stream>>>(Wq, Wk, Wv, Wqk_t, Wv_t);
  transpose_cvt<<<dim3(128, 32), 256, 0, stream>>>(W1, W1t, D, DF);
  transpose_cvt<<<dim3(32, 128), 256, 0, stream>>>(W2, W2t, DF, D);
  // 2. LN1
  ln_bf16<<<M, 256, 0, stream>>>(x, g1, be1, xnorm);
  // 3. QK projection (fused Wq|Wk)
  gemm_bt<0><<<(M / 128) * (2048 / 128), 256, 0, stream>>>(
      xnorm, Wqk_t, QK, nullptr, nullptr, M, 2048, D);
  // 4. V projection transposed
  gemm_bt<0><<<(D / 128) * (M / 128), 256, 0, stream>>>(
      Wv_t, xnorm, Vt, nullptr, nullptr, D, M, D);
  // 5. attention
  attn_fwd<<<dim3(16, 32), 512, 0, stream>>>(QK, Vt, attnO);
  // 6. residual + LN2
  add_ln_bf16<<<M, 256, 0, stream>>>(attnO, x, g2, be2, xres, xnorm2);
  // 7. FFN1 (bias + relu fused), 256^2-tile kernel
  gemm256_bt<1><<<(M / 256) * (DF / 256), 512, 0, stream>>>(
      xres, W1t, hbuf, b1, M, DF, D);
  // 8. FFN2 split-K=2 (grid 512 = 2 blocks/CU): partials -> part0, out
  gemm_splitk<<<dim3((M / 128) * (D / 128), 2), 256, 0, stream>>>(
      hbuf, W2t, part0, out, M, D, DF, DF / 2);
  // 9. FFN2 epilogue: out = part0 + out + bias + xnorm2
  ffn2_epi<<<M, 256, 0, stream>>>(part0, out, b2, xnorm2);
}